// Round 12
// baseline (211.372 us; speedup 1.0000x reference)
//
#include <hip/hip_runtime.h>
#include <math.h>

// Problem constants
#define B_   4
#define N_   4096
#define K_   32
#define C_   192
#define CH_  195          // C + 3 (logical GEMM K)
#define KPAD 224          // 7 x 32 ; g_Wp cols: 0..191=channels, 192..194=dp, 195..223=0
#define NKT6 6            // K-tiles in LDS (kt=6 built from s_d in registers)
#define NNT8 8            // N-tiles per iteration (128 cols = 2 pairs)
#define GRID 512          // 256 CU x 2 resident blocks — ALL co-resident (grid sync safe)

using half8  = __attribute__((ext_vector_type(8))) _Float16;
using half2v = __attribute__((ext_vector_type(2))) _Float16;
using f32x4  = __attribute__((ext_vector_type(4))) float;

// Module-static device scratch
__device__ _Float16 g_Wp[C_ * KPAD];                    // 86016 B (rows pre-scaled by BN inv)
__device__ _Float16 g_xT[(size_t)B_ * N_ * C_];         // 6291456 B
__device__ unsigned int g_ctr;                          // .bss zero-init; monotonic across replays

// ---- single fused kernel (R12): prep folded in via generation-counter grid sync ----
// R1-R11 ledger: dur_us - la_mfma = 63-70 us INVARIANT. This kernel eliminates the
// separate prep launch + stream gap entirely. Phase 0: 512 blocks transpose x->g_xT
// (one 32-pt tile each) + convert W (blocks<168). Grid sync: gen = atomicAdd/512,
// spin to (gen+1)*512 — monotonic, graph-replay-safe; acq_rel agent scope + fences
// handle cross-XCD L2 visibility. Main loop = R9 verbatim (best core: 81us, 2-pair
// batch, 4 waves, acc[3][8], transposed MFMA, W streamed from L2).
__global__ __launch_bounds__(256, 2) void la_fused(
    const float* __restrict__ p,      // [B,N,3]
    const float* __restrict__ x,      // [B,C,N]
    const int*   __restrict__ idx,    // [B,N,K]
    const float* __restrict__ W,      // [C, C+3]
    const float* __restrict__ gamma_,
    const float* __restrict__ beta_,
    const float* __restrict__ rmean,
    const float* __restrict__ rvar,
    float* __restrict__ out)          // [B,C,N]
{
    __shared__ unsigned char s_raw[49152];          // hb (49152B) ALIASES ts (25728B)
    __shared__ float s_d[3][128];                   // per-col dp (kt=6 built in regs)
    __shared__ float s_bias[C_], s_fr[32];

    _Float16* hb = (_Float16*)s_raw;                // [NKT6*NNT8*64*8] frag-order tile
    float (*ts)[201] = (float(*)[201])s_raw;        // [32][201] transpose staging

    const int tid  = threadIdx.x;
    const int lane = tid & 63;
    const int w    = tid >> 6;        // 0..3
    const int l15  = lane & 15;
    const int quad = lane >> 4;
    const int bid  = blockIdx.x;

    // ================= PHASE 0: prep (was a separate kernel) =================
    // 0A: W conversion — blocks 0..167, 1 element/thread (168*256 = 43008 = C*KPAD)
    if (bid < 168) {
        const int i = bid * 256 + tid;
        const int o = i / KPAD, r = i - o * KPAD;
        const float inv = gamma_[o] * rsqrtf(rvar[o] + 1e-5f);  // BN scale folded into W
        float v = 0.0f;
        if (r < 192)      v = W[o * CH_ + 3 + r];      // channel weights
        else if (r < 195) v = W[o * CH_ + (r - 192)];  // dp weights
        g_Wp[i] = (_Float16)(v * inv);
    }
    // 0B: transpose x -> g_xT — block bid owns (b = bid>>7, n-tile = bid&127)
    {
        const int tb = bid >> 7;
        const int n0 = (bid & 127) * 32;
        const int cl = tid >> 3;                 // 0..31 channel-within-iter
        const int n4 = (tid & 7) * 4;            // 0..28, x4 floats
#pragma unroll
        for (int it = 0; it < 6; ++it) {
            const int c = it * 32 + cl;
            const float4 v = *(const float4*)(x + ((size_t)tb * C_ + c) * N_ + n0 + n4);
            ts[n4 + 0][c] = v.x; ts[n4 + 1][c] = v.y; ts[n4 + 2][c] = v.z; ts[n4 + 3][c] = v.w;
        }
        __syncthreads();
        const int n  = tid >> 3;                 // 0..31
        const int og = tid & 7;                  // octet-group
#pragma unroll
        for (int it = 0; it < 3; ++it) {
            const int oc = it * 8 + og;          // 0..23 channel octet
            half8 v;
#pragma unroll
            for (int jj = 0; jj < 8; ++jj) v[jj] = (_Float16)ts[n][oc * 8 + jj];
            *(half8*)(g_xT + ((size_t)tb * N_ + n0 + n) * C_ + oc * 8) = v;
        }
    }

    // ---- grid sync: generation counter (replay-safe: gen = arrivals/512) ----
    __syncthreads();                  // drains vmcnt(0): all our global writes issued
    if (tid == 0) {
        __threadfence();              // release: g_xT/g_Wp visible device-wide
        const unsigned a = __hip_atomic_fetch_add(&g_ctr, 1u, __ATOMIC_ACQ_REL,
                                                  __HIP_MEMORY_SCOPE_AGENT);
        const unsigned target = (a / (unsigned)GRID + 1u) * (unsigned)GRID;
        while (__hip_atomic_load(&g_ctr, __ATOMIC_ACQUIRE,
                                 __HIP_MEMORY_SCOPE_AGENT) < target) {
            __builtin_amdgcn_s_sleep(2);
        }
        __threadfence();              // acquire: invalidate stale L1/L2 before gathers
    }
    __syncthreads();

    // ================= MAIN: R9 core, verbatim =================
    // XCD-chunked: xcd owns pairs [xcd*1024, +1024); 64 slots x 16 pairs = 8 iters x 2.
    const int xcd      = bid & 7;
    const int slot     = bid >> 3;                     // 0..63
    const int pairbase = xcd * 1024 + slot * 16;
    const int iters    = 8;
    const int b        = xcd >> 1;

    if (tid < C_) {
        const float inv = gamma_[tid] * rsqrtf(rvar[tid] + 1e-5f);
        s_bias[tid] = beta_[tid] - rmean[tid] * inv;   // scale part lives in g_Wp
    }
    // s_fr[f] = (50 / 2pi) * 500^(-f/32)   (v_sin takes revolutions)
    if (tid < 32) s_fr[tid] = 7.9577471546f * exp2f(-(float)tid * 0.2801808715263400f);
    __syncthreads();

    float sfr[8];
#pragma unroll
    for (int jj = 0; jj < 8; ++jj) sfr[jj] = s_fr[quad * 8 + jj];

    const int pt = w >> 1;                    // wave-uniform point-within-pair
    const int k  = (w & 1) * 16 + l15;        // neighbor slot 0..31

    // prefetch gather indices for iteration 0 (2 scalars — safe)
    int j0 = idx[(size_t)((pairbase + 0) * 2 + pt) * K_ + k];
    int j1 = idx[(size_t)((pairbase + 1) * 2 + pt) * K_ + k];

    for (int it = 0; it < iters; ++it) {
        const int pr0 = pairbase + 2 * it;
        const int n0  = (pr0 * 2) & (N_ - 1);

        // ---- Phase B: build BOTH pairs' columns (128 cols) into hb ----
#pragma unroll
        for (int pp = 0; pp < 2; ++pp) {
            const int j  = pp ? j1 : j0;
            const int gp = (pr0 + pp) * 2 + pt;
            const float d0 = p[(size_t)(b * N_ + j) * 3 + 0] - p[(size_t)gp * 3 + 0];
            const float d1 = p[(size_t)(b * N_ + j) * 3 + 1] - p[(size_t)gp * 3 + 1];
            const float d2 = p[(size_t)(b * N_ + j) * 3 + 2] - p[(size_t)gp * 3 + 2];
            const _Float16* xh = g_xT + ((size_t)b * N_ + j) * C_;
            const int nt = pp * 4 + w;         // n-tile of this column

#pragma unroll
            for (int i6 = 0; i6 < 6; ++i6) {
                const int chunk = quad + 4 * i6;           // channel octet 0..23; kt = i6
                const half8 v = *(const half8*)(xh + chunk * 8);
                const float dd  = (chunk < 8) ? d0 : ((chunk < 16) ? d1 : d2);
                const float off = (chunk & 4) ? 0.25f : 0.0f;   // cos = sin(+1/4 rev)
                half8 hv;
#pragma unroll
                for (int jj = 0; jj < 8; jj += 2) {
                    const float pe0 = __builtin_amdgcn_sinf(fmaf(dd, sfr[jj],     off));
                    const float pe1 = __builtin_amdgcn_sinf(fmaf(dd, sfr[jj + 1], off));
                    const half2v pe2 = __builtin_bit_cast(half2v, __builtin_amdgcn_cvt_pkrtz(pe0, pe1));
                    half2v v2; v2[0] = v[jj]; v2[1] = v[jj + 1];
                    const half2v r2 = pe2 * v2 + pe2;   // v_pk_fma_f16: pe*(x+1)
                    hv[jj] = r2[0]; hv[jj + 1] = r2[1];
                }
                *(half8*)(&hb[(size_t)((i6 * NNT8 + nt) * 64 + quad * 16 + l15) * 8]) = hv;
            }
            if (quad == 0) {     // dp for col -> s_d (kt=6 built in regs at consume)
                const int col = nt * 16 + l15;
                s_d[0][col] = d0; s_d[1][col] = d1; s_d[2][col] = d2;
            }
        }
        __syncthreads();        // hb + s_d complete

        // prefetch next iteration's gather indices under phase C
        if (it + 1 < iters) {
            j0 = idx[(size_t)((pr0 + 2) * 2 + pt) * K_ + k];
            j1 = idx[(size_t)((pr0 + 3) * 2 + pt) * K_ + k];
        }

        // ---- Phase C: transposed MFMA over 128 cols; each W-frag reused 8x ----
        f32x4 acc[3][8];
#pragma unroll
        for (int i = 0; i < 3; ++i)
#pragma unroll
            for (int t = 0; t < 8; ++t) acc[i][t] = (f32x4)0.0f;

#pragma unroll
        for (int kt = 0; kt < NKT6; ++kt) {
            const int k0 = kt * 32 + quad * 8;
            half8 a[3];
#pragma unroll
            for (int i = 0; i < 3; ++i)
                a[i] = *(const half8*)(g_Wp + (size_t)((w * 3 + i) * 16 + l15) * KPAD + k0);
#pragma unroll
            for (int t = 0; t < 8; ++t) {
                const half8 bf = *(const half8*)(&hb[(size_t)((kt * NNT8 + t) * 64 + lane) * 8]);
#pragma unroll
                for (int i = 0; i < 3; ++i)   // A=h-frag, B=W-frag -> D = (W.h)^T
                    acc[i][t] = __builtin_amdgcn_mfma_f32_16x16x32_f16(bf, a[i], acc[i][t], 0, 0, 0);
            }
        }
        // kt = 6: dp rows 192..194 (only quad 0's k-range 0..7 has nonzero rows)
        {
            half8 a6[3];
#pragma unroll
            for (int i = 0; i < 3; ++i)
                a6[i] = *(const half8*)(g_Wp + (size_t)((w * 3 + i) * 16 + l15) * KPAD + 6 * 32 + quad * 8);
#pragma unroll
            for (int t = 0; t < 8; ++t) {
                const int col = t * 16 + l15;
                half8 b6 = (half8)(_Float16)0.0f;
                const float e0 = s_d[0][col];   // quads read same addr -> broadcast
                const float e1 = s_d[1][col];
                const float e2 = s_d[2][col];
                if (quad == 0) {
                    b6[0] = (_Float16)e0; b6[1] = (_Float16)e1; b6[2] = (_Float16)e2;
                }
#pragma unroll
                for (int i = 0; i < 3; ++i)
                    acc[i][t] = __builtin_amdgcn_mfma_f32_16x16x32_f16(b6, a6[i], acc[i][t], 0, 0, 0);
            }
        }

        // ---- Epilogue: tile t = pp*4 + {0,1|2,3} -> point n0 + pp*2 + ptc ----
        // 8 in-lane fmax + cross-quad butterfly; float4 store (4 consecutive points).
#pragma unroll
        for (int i = 0; i < 3; ++i) {
            const int m = (w * 3 + i) * 16 + l15;
            float4 o4;
            float ov[4];
#pragma unroll
            for (int pp = 0; pp < 2; ++pp)
#pragma unroll
                for (int ptc = 0; ptc < 2; ++ptc) {
                    const f32x4 va = acc[i][pp * 4 + 2 * ptc];
                    const f32x4 vb = acc[i][pp * 4 + 2 * ptc + 1];
                    float v = fmaxf(fmaxf(fmaxf(va[0], va[1]), fmaxf(va[2], va[3])),
                                    fmaxf(fmaxf(vb[0], vb[1]), fmaxf(vb[2], vb[3])));
                    v = fmaxf(v, __shfl_xor(v, 16, 64));
                    v = fmaxf(v, __shfl_xor(v, 32, 64));
                    ov[pp * 2 + ptc] = v;
                }
            if (quad == 0) {
                const float bias = s_bias[m];
                o4.x = fmaxf(ov[0] + bias, 0.0f);
                o4.y = fmaxf(ov[1] + bias, 0.0f);
                o4.z = fmaxf(ov[2] + bias, 0.0f);
                o4.w = fmaxf(ov[3] + bias, 0.0f);
                *(float4*)(&out[((size_t)b * C_ + m) * N_ + n0]) = o4;
            }
        }
        __syncthreads();   // all hb/s_d reads done before next build overwrites
    }
}

extern "C" void kernel_launch(void* const* d_in, const int* in_sizes, int n_in,
                              void* d_out, int out_size, void* d_ws, size_t ws_size,
                              hipStream_t stream) {
    (void)in_sizes; (void)n_in; (void)out_size; (void)d_ws; (void)ws_size;
    const float* p      = (const float*)d_in[0];
    const float* x      = (const float*)d_in[1];
    const int*   idx    = (const int*)d_in[2];
    const float* W      = (const float*)d_in[3];
    const float* gamma_ = (const float*)d_in[4];
    const float* beta_  = (const float*)d_in[5];
    const float* rmean  = (const float*)d_in[6];
    const float* rvar   = (const float*)d_in[7];
    float* out = (float*)d_out;

    la_fused<<<GRID, 256, 0, stream>>>(p, x, idx, W, gamma_, beta_, rmean, rvar, out);
}

// Round 15
// 145.835 us; speedup vs baseline: 1.4494x; 1.4494x over previous
//
#include <hip/hip_runtime.h>
#include <math.h>

// Problem constants
#define B_   4
#define N_   4096
#define K_   32
#define C_   192
#define CH_  195          // C + 3 (logical GEMM K)
#define KPAD 224          // 7 x 32 ; g_Wp cols: 0..191=channels, 192..194=dp, 195..223=0
#define NKT6 6            // K-tiles in LDS (kt=6 built from s_d in registers)
#define NNT8 8            // N-tiles per iteration (128 cols = 2 pairs)
#define GRID 512          // 256 CU x 2 resident blocks (quasi-persistent)

using half8  = __attribute__((ext_vector_type(8))) _Float16;
using half2v = __attribute__((ext_vector_type(2))) _Float16;
using f32x4  = __attribute__((ext_vector_type(4))) float;

// Module-static device scratch
__device__ _Float16 g_Wp[C_ * KPAD];                    // 86016 B (rows pre-scaled by BN inv)
__device__ _Float16 g_xT[(size_t)B_ * N_ * C_];         // 6291456 B

// ---- fused prep: blocks 0..511 transpose x -> g_xT ; blocks 512.. convert W ----
// (R12 proved prep-as-kernel costs only ~9us; fusion regressed. Keep separate.)
__global__ __launch_bounds__(256) void prep(const float* __restrict__ x,
                                            const float* __restrict__ W,
                                            const float* __restrict__ gamma_,
                                            const float* __restrict__ rvar) {
    const int tid = threadIdx.x;
    if (blockIdx.x < 512) {
        __shared__ float s[32][201];
        const int b  = blockIdx.x >> 7;          // 4 batches x 128 tiles
        const int n0 = (blockIdx.x & 127) * 32;
        const int cl = tid >> 3;                 // 0..31 channel-within-iter
        const int n4 = (tid & 7) * 4;            // 0..28, x4 floats
#pragma unroll
        for (int it = 0; it < 6; ++it) {
            const int c = it * 32 + cl;
            const float4 v = *(const float4*)(x + ((size_t)b * C_ + c) * N_ + n0 + n4);
            s[n4 + 0][c] = v.x; s[n4 + 1][c] = v.y; s[n4 + 2][c] = v.z; s[n4 + 3][c] = v.w;
        }
        __syncthreads();
        const int n  = tid >> 3;                 // 0..31
        const int og = tid & 7;                  // octet-group
#pragma unroll
        for (int it = 0; it < 3; ++it) {
            const int oc = it * 8 + og;          // 0..23 channel octet
            half8 v;
#pragma unroll
            for (int jj = 0; jj < 8; ++jj) v[jj] = (_Float16)s[n][oc * 8 + jj];
            *(half8*)(g_xT + ((size_t)b * N_ + n0 + n) * C_ + oc * 8) = v;
        }
    } else {
        const int i = (blockIdx.x - 512) * 256 + tid;
        if (i < C_ * KPAD) {
            const int o = i / KPAD, r = i - o * KPAD;
            const float inv = gamma_[o] * rsqrtf(rvar[o] + 1e-5f);  // BN scale folded into W
            float v = 0.0f;
            if (r < 192)      v = W[o * CH_ + 3 + r];      // channel weights
            else if (r < 195) v = W[o * CH_ + (r - 192)];  // dp weights
            g_Wp[i] = (_Float16)(v * inv);
        }
    }
}

// ---- main fused kernel (R14): R9 core + latency pipelining, register-safe ----
// R13 (unmeasured, 2x container fail) risked the 256-reg cap (acc 96 + bfC 32 +
// bfN 32 + aC/aN 24 + misc). R14 drops ONLY the bfN LDS prefetch (32 regs to hide
// the ~120cyc short pole); keeps: (1) aN W-load rotation one kt ahead (~250cyc L2
// long pole), (2) phase-B full gather hoist (all loads issued before sin chain),
// (3) s_setprio(1) around MFMA clusters. Peak regs ~190-215 < 256 cap at (256,2).
__global__ __launch_bounds__(256, 2) void la_mfma(
    const float* __restrict__ p,      // [B,N,3]
    const int*   __restrict__ idx,    // [B,N,K]
    const float* __restrict__ gamma_,
    const float* __restrict__ beta_,
    const float* __restrict__ rmean,
    const float* __restrict__ rvar,
    float* __restrict__ out)          // [B,C,N]
{
    __shared__ _Float16 hb[NKT6 * NNT8 * 64 * 8];   // 49152 B
    __shared__ float s_d[3][128];                   // per-col dp (kt=6 built in regs)
    __shared__ float s_bias[C_], s_fr[32];

    const int tid  = threadIdx.x;
    const int lane = tid & 63;
    const int w    = tid >> 6;
    const int l15  = lane & 15;
    const int quad = lane >> 4;

    // XCD-chunked: xcd owns pairs [xcd*1024, +1024); 64 slots x 16 pairs = 8 iters x 2.
    const int xcd      = blockIdx.x & 7;
    const int slot     = blockIdx.x >> 3;              // 0..63
    const int pairbase = xcd * 1024 + slot * 16;
    const int iters    = 8;
    const int b        = xcd >> 1;

    if (tid < C_) {
        const float inv = gamma_[tid] * rsqrtf(rvar[tid] + 1e-5f);
        s_bias[tid] = beta_[tid] - rmean[tid] * inv;   // scale part lives in g_Wp
    }
    // s_fr[f] = (50 / 2pi) * 500^(-f/32)   (v_sin takes revolutions)
    if (tid < 32) s_fr[tid] = 7.9577471546f * exp2f(-(float)tid * 0.2801808715263400f);
    __syncthreads();

    float sfr[8];
#pragma unroll
    for (int jj = 0; jj < 8; ++jj) sfr[jj] = s_fr[quad * 8 + jj];

    const int pt = w >> 1;                    // wave-uniform point-within-pair
    const int k  = (w & 1) * 16 + l15;        // neighbor slot 0..31

    // prefetch gather indices for iteration 0 (2 scalars — safe)
    int j0 = idx[(size_t)((pairbase + 0) * 2 + pt) * K_ + k];
    int j1 = idx[(size_t)((pairbase + 1) * 2 + pt) * K_ + k];

    for (int it = 0; it < iters; ++it) {
        const int pr0 = pairbase + 2 * it;
        const int n0  = (pr0 * 2) & (N_ - 1);

        // ---- Phase B, stage 1: issue ALL gather loads for BOTH pairs up front ----
        half8 vx[2][6];          // 12 x half8 (48 VGPR, phase-B-local)
        float pj[2][3], px[2][3];
#pragma unroll
        for (int pp = 0; pp < 2; ++pp) {
            const int j  = pp ? j1 : j0;
            const int gp = (pr0 + pp) * 2 + pt;
            const _Float16* xh = g_xT + ((size_t)b * N_ + j) * C_;
#pragma unroll
            for (int i6 = 0; i6 < 6; ++i6)
                vx[pp][i6] = *(const half8*)(xh + (quad + 4 * i6) * 8);
#pragma unroll
            for (int c = 0; c < 3; ++c) {
                pj[pp][c] = p[(size_t)(b * N_ + j) * 3 + c];
                px[pp][c] = p[(size_t)gp * 3 + c];
            }
        }

        // ---- Phase B, stage 2: sin chain + frag-order build (loads in flight) ----
#pragma unroll
        for (int pp = 0; pp < 2; ++pp) {
            const float d0 = pj[pp][0] - px[pp][0];
            const float d1 = pj[pp][1] - px[pp][1];
            const float d2 = pj[pp][2] - px[pp][2];
            const int nt = pp * 4 + w;         // n-tile of this column
#pragma unroll
            for (int i6 = 0; i6 < 6; ++i6) {
                const int chunk = quad + 4 * i6;           // channel octet 0..23; kt = i6
                const half8 v = vx[pp][i6];
                const float dd  = (chunk < 8) ? d0 : ((chunk < 16) ? d1 : d2);
                const float off = (chunk & 4) ? 0.25f : 0.0f;   // cos = sin(+1/4 rev)
                half8 hv;
#pragma unroll
                for (int jj = 0; jj < 8; jj += 2) {
                    const float pe0 = __builtin_amdgcn_sinf(fmaf(dd, sfr[jj],     off));
                    const float pe1 = __builtin_amdgcn_sinf(fmaf(dd, sfr[jj + 1], off));
                    const half2v pe2 = __builtin_bit_cast(half2v, __builtin_amdgcn_cvt_pkrtz(pe0, pe1));
                    half2v v2; v2[0] = v[jj]; v2[1] = v[jj + 1];
                    const half2v r2 = pe2 * v2 + pe2;   // v_pk_fma_f16: pe*(x+1)
                    hv[jj] = r2[0]; hv[jj + 1] = r2[1];
                }
                *(half8*)(&hb[(size_t)((i6 * NNT8 + nt) * 64 + quad * 16 + l15) * 8]) = hv;
            }
            if (quad == 0) {     // dp for col -> s_d (kt=6 built in regs at consume)
                const int col = nt * 16 + l15;
                s_d[0][col] = d0; s_d[1][col] = d1; s_d[2][col] = d2;
            }
        }
        __syncthreads();        // hb + s_d complete

        // prefetch next iteration's gather indices under phase C
        if (it + 1 < iters) {
            j0 = idx[(size_t)((pr0 + 2) * 2 + pt) * K_ + k];
            j1 = idx[(size_t)((pr0 + 3) * 2 + pt) * K_ + k];
        }

        // ---- Phase C: transposed MFMA; W-loads (the L2 long pole) rotate 1 kt ahead ----
        f32x4 acc[3][8];
#pragma unroll
        for (int i = 0; i < 3; ++i)
#pragma unroll
            for (int t = 0; t < 8; ++t) acc[i][t] = (f32x4)0.0f;

        half8 aC[3];
#pragma unroll
        for (int i = 0; i < 3; ++i)
            aC[i] = *(const half8*)(g_Wp + ((size_t)((w * 3 + i) * 16 + l15)) * KPAD + quad * 8);

#pragma unroll
        for (int kt = 0; kt < NKT6; ++kt) {
            half8 aN[3];
            const int kn = kt + 1;                 // 1..6 (kn=6 -> dp tile's W frags)
#pragma unroll
            for (int i = 0; i < 3; ++i)
                aN[i] = *(const half8*)(g_Wp + ((size_t)((w * 3 + i) * 16 + l15)) * KPAD + kn * 32 + quad * 8);
            __builtin_amdgcn_s_setprio(1);
#pragma unroll
            for (int t = 0; t < 8; ++t) {
                const half8 bf = *(const half8*)(&hb[(size_t)((kt * NNT8 + t) * 64 + lane) * 8]);
#pragma unroll
                for (int i = 0; i < 3; ++i)   // A=h-frag, B=W-frag -> D = (W.h)^T
                    acc[i][t] = __builtin_amdgcn_mfma_f32_16x16x32_f16(bf, aC[i], acc[i][t], 0, 0, 0);
            }
            __builtin_amdgcn_s_setprio(0);
#pragma unroll
            for (int i = 0; i < 3; ++i) aC[i] = aN[i];
        }
        // kt = 6: dp rows 192..194; aC holds the kt=6 W-fragments from the rotation.
        {
            __builtin_amdgcn_s_setprio(1);
#pragma unroll
            for (int t = 0; t < 8; ++t) {
                const int col = t * 16 + l15;
                half8 b6 = (half8)(_Float16)0.0f;
                const float e0 = s_d[0][col];   // quads read same addr -> broadcast
                const float e1 = s_d[1][col];
                const float e2 = s_d[2][col];
                if (quad == 0) {
                    b6[0] = (_Float16)e0; b6[1] = (_Float16)e1; b6[2] = (_Float16)e2;
                }
#pragma unroll
                for (int i = 0; i < 3; ++i)
                    acc[i][t] = __builtin_amdgcn_mfma_f32_16x16x32_f16(b6, aC[i], acc[i][t], 0, 0, 0);
            }
            __builtin_amdgcn_s_setprio(0);
        }

        // ---- Epilogue: tile t = pp*4 + {0,1|2,3} -> point n0 + pp*2 + ptc ----
        // 8 in-lane fmax + cross-quad butterfly; float4 store (4 consecutive points).
#pragma unroll
        for (int i = 0; i < 3; ++i) {
            const int m = (w * 3 + i) * 16 + l15;
            float4 o4;
            float ov[4];
#pragma unroll
            for (int pp = 0; pp < 2; ++pp)
#pragma unroll
                for (int ptc = 0; ptc < 2; ++ptc) {
                    const f32x4 va = acc[i][pp * 4 + 2 * ptc];
                    const f32x4 vb = acc[i][pp * 4 + 2 * ptc + 1];
                    float v = fmaxf(fmaxf(fmaxf(va[0], va[1]), fmaxf(va[2], va[3])),
                                    fmaxf(fmaxf(vb[0], vb[1]), fmaxf(vb[2], vb[3])));
                    v = fmaxf(v, __shfl_xor(v, 16, 64));
                    v = fmaxf(v, __shfl_xor(v, 32, 64));
                    ov[pp * 2 + ptc] = v;
                }
            if (quad == 0) {
                const float bias = s_bias[m];
                o4.x = fmaxf(ov[0] + bias, 0.0f);
                o4.y = fmaxf(ov[1] + bias, 0.0f);
                o4.z = fmaxf(ov[2] + bias, 0.0f);
                o4.w = fmaxf(ov[3] + bias, 0.0f);
                *(float4*)(&out[((size_t)b * C_ + m) * N_ + n0]) = o4;
            }
        }
        __syncthreads();   // all hb/s_d reads done before next build overwrites
    }
}

extern "C" void kernel_launch(void* const* d_in, const int* in_sizes, int n_in,
                              void* d_out, int out_size, void* d_ws, size_t ws_size,
                              hipStream_t stream) {
    (void)in_sizes; (void)n_in; (void)out_size; (void)d_ws; (void)ws_size;
    const float* p      = (const float*)d_in[0];
    const float* x      = (const float*)d_in[1];
    const int*   idx    = (const int*)d_in[2];
    const float* W      = (const float*)d_in[3];
    const float* gamma_ = (const float*)d_in[4];
    const float* beta_  = (const float*)d_in[5];
    const float* rmean  = (const float*)d_in[6];
    const float* rvar   = (const float*)d_in[7];
    float* out = (float*)d_out;

    prep<<<512 + (C_ * KPAD + 255) / 256, 256, 0, stream>>>(x, W, gamma_, rvar);
    la_mfma<<<GRID, 256, 0, stream>>>(p, idx, gamma_, beta_, rmean, rvar, out);
}